// Round 1
// baseline (4031.521 us; speedup 1.0000x reference)
//
#include <hip/hip_runtime.h>
#include <hip/hip_bf16.h>

#define TT 4096
#define FF 80
#define HH 64

__device__ __forceinline__ float sigm(float x) {
    // 1/(1+e^-x); rcp approx error ~1 ulp, fine vs 9.6e-3 tolerance
    return __builtin_amdgcn_rcpf(1.0f + __expf(-x));
}
__device__ __forceinline__ float tanh_f(float x) {
    // tanh(x) = 1 - 2/(e^{2x}+1); saturates correctly at +/-1 for large |x|
    return 1.0f - 2.0f * __builtin_amdgcn_rcpf(1.0f + __expf(2.0f * x));
}

// One block per (direction, batch) sequence: 256 blocks, 256 threads (4 waves).
// Thread k owns gate row k (i:0-63, f:64-127, g:128-191, o:192-255), with its
// W_ih row (80 f32) and W_hh row (64 f32) in registers. Per step:
//   gate_k = bias_k + W_ih[k,:].x[t] + W_hh[k,:].h   (x[t] and h broadcast from LDS)
// then one barrier, then every wave redundantly does the 64 elementwise c/h
// updates (lane = hidden unit) and rewrites its OWN per-wave h buffer (no 2nd
// barrier needed; same-wave LDS ordering is guaranteed via lgkmcnt).
__global__ __launch_bounds__(256, 1)
void lstm_scan_kernel(const float* __restrict__ x,
                      const float* __restrict__ w_ih_f, const float* __restrict__ w_hh_f,
                      const float* __restrict__ b_ih_f, const float* __restrict__ b_hh_f,
                      const float* __restrict__ w_ih_b, const float* __restrict__ w_hh_b,
                      const float* __restrict__ b_ih_b, const float* __restrict__ b_hh_b,
                      float* __restrict__ h_out)   // [2][128][64]
{
    const int blk = blockIdx.x;       // 0..255
    const int dir = blk >> 7;         // 0 = fwd, 1 = bwd (time-reversed)
    const int bat = blk & 127;
    const int tid = threadIdx.x;      // == gate index k
    const int wv  = tid >> 6;
    const int ln  = tid & 63;

    const float* __restrict__ w_ih = dir ? w_ih_b : w_ih_f;
    const float* __restrict__ w_hh = dir ? w_hh_b : w_hh_f;
    const float* __restrict__ b_ih = dir ? b_ih_b : b_ih_f;
    const float* __restrict__ b_hh = dir ? b_hh_b : b_hh_f;

    // register-resident weight rows for this thread's gate
    float wi[FF], wh[HH];
    #pragma unroll
    for (int f = 0; f < FF; ++f) wi[f] = w_ih[tid * FF + f];
    #pragma unroll
    for (int j = 0; j < HH; ++j) wh[j] = w_hh[tid * HH + j];
    const float bias = b_ih[tid] + b_hh[tid];

    __shared__ float xs[2][FF];       // x[t] double buffer
    __shared__ float hbuf[4][HH];     // per-wave private h copy
    __shared__ float gbuf[2][256];    // pre-activation gates, double buffered

    const float* __restrict__ xrow = x + (size_t)bat * (TT * FF);

    float c = 0.0f, hreg = 0.0f;
    hbuf[wv][ln] = 0.0f;

    // prime x pipeline: xs[0] = x(t_eff(0)); xA holds x(t_eff(1))
    float xA = 0.0f;
    if (tid < FF) {
        xs[0][tid] = xrow[(size_t)(dir ? (TT - 1) : 0) * FF + tid];
        xA         = xrow[(size_t)(dir ? (TT - 2) : 1) * FF + tid];
    }
    __syncthreads();

    #pragma unroll 1
    for (int t = 0; t < TT; ++t) {
        const int cur = t & 1, nxt = cur ^ 1;

        float a0 = 0.f, a1 = 0.f, a2 = 0.f, a3 = 0.f;
        const float4* xs4 = reinterpret_cast<const float4*>(xs[cur]);
        #pragma unroll
        for (int f = 0; f < FF / 4; ++f) {
            float4 v = xs4[f];
            a0 = fmaf(wi[4*f+0], v.x, a0);
            a1 = fmaf(wi[4*f+1], v.y, a1);
            a2 = fmaf(wi[4*f+2], v.z, a2);
            a3 = fmaf(wi[4*f+3], v.w, a3);
        }
        const float4* hb4 = reinterpret_cast<const float4*>(hbuf[wv]);
        #pragma unroll
        for (int j = 0; j < HH / 4; ++j) {
            float4 v = hb4[j];
            a0 = fmaf(wh[4*j+0], v.x, a0);
            a1 = fmaf(wh[4*j+1], v.y, a1);
            a2 = fmaf(wh[4*j+2], v.z, a2);
            a3 = fmaf(wh[4*j+3], v.w, a3);
        }
        const float gate = ((a0 + a1) + (a2 + a3)) + bias;
        gbuf[cur][tid] = gate;

        // stage x for t+1 (loaded last iteration), issue load for t+2
        if (tid < FF) {
            if (t + 1 < TT) xs[nxt][tid] = xA;
            if (t + 2 < TT) xA = xrow[(size_t)(dir ? (TT - 3 - t) : (t + 2)) * FF + tid];
        }
        __syncthreads();   // gates (and next x) visible

        // elementwise update, redundantly on every wave (lane = hidden unit)
        const float gi = gbuf[cur][ln];
        const float gf = gbuf[cur][64 + ln];
        const float gg = gbuf[cur][128 + ln];
        const float go = gbuf[cur][192 + ln];
        c    = sigm(gf) * c + sigm(gi) * tanh_f(gg);
        hreg = sigm(go) * tanh_f(c);
        hbuf[wv][ln] = hreg;   // own-wave buffer: no barrier needed
    }

    if (tid < HH) h_out[(size_t)(dir * 128 + bat) * HH + tid] = hreg;
}

// out[b][o] = b_fc[o] + sum_j h_fwd[b][j]*w_fc[o][j] + sum_j h_bwd[b][j]*w_fc[o][64+j]
__global__ __launch_bounds__(64, 1)
void fc_kernel(const float* __restrict__ h_out,   // [2][128][64]
               const float* __restrict__ w_fc,    // [8][128]
               const float* __restrict__ b_fc,    // [8]
               float* __restrict__ out)           // [128][8]
{
    const int b = blockIdx.x;      // 0..127
    const int o = threadIdx.x;     // 0..63, active 0..7
    if (o < 8) {
        float acc = b_fc[o];
        #pragma unroll 4
        for (int j = 0; j < HH; ++j)
            acc = fmaf(h_out[(size_t)b * HH + j], w_fc[o * 128 + j], acc);
        #pragma unroll 4
        for (int j = 0; j < HH; ++j)
            acc = fmaf(h_out[(size_t)(128 + b) * HH + j], w_fc[o * 128 + 64 + j], acc);
        out[b * 8 + o] = acc;
    }
}

extern "C" void kernel_launch(void* const* d_in, const int* in_sizes, int n_in,
                              void* d_out, int out_size, void* d_ws, size_t ws_size,
                              hipStream_t stream) {
    const float* x      = (const float*)d_in[0];
    // d_in[1] = lengths (unused by the reference forward)
    const float* w_ih_f = (const float*)d_in[2];
    const float* w_hh_f = (const float*)d_in[3];
    const float* b_ih_f = (const float*)d_in[4];
    const float* b_hh_f = (const float*)d_in[5];
    const float* w_ih_b = (const float*)d_in[6];
    const float* w_hh_b = (const float*)d_in[7];
    const float* b_ih_b = (const float*)d_in[8];
    const float* b_hh_b = (const float*)d_in[9];
    const float* w_fc   = (const float*)d_in[10];
    const float* b_fc   = (const float*)d_in[11];
    float* out   = (float*)d_out;
    float* h_out = (float*)d_ws;   // 2*128*64 f32 = 64 KiB scratch

    lstm_scan_kernel<<<dim3(256), dim3(256), 0, stream>>>(
        x, w_ih_f, w_hh_f, b_ih_f, b_hh_f,
        w_ih_b, w_hh_b, b_ih_b, b_hh_b, h_out);

    fc_kernel<<<dim3(128), dim3(64), 0, stream>>>(h_out, w_fc, b_fc, out);
}